// Round 6
// baseline (811.063 us; speedup 1.0000x reference)
//
#include <hip/hip_runtime.h>

#define H 128

__global__ void fill_u32(unsigned* __restrict__ p, unsigned v, int n) {
    int i = blockIdx.x * blockDim.x + threadIdx.x;
    if (i < n) p[i] = v;
}

// ---------------- fuse: one wave per node, weights in padded LDS ----------------
__global__ void fuse_kernel(const float* __restrict__ x,
                            const float* __restrict__ sat_w, const float* __restrict__ sat_b,
                            const float* __restrict__ neigh_w, const float* __restrict__ neigh_b,
                            const float* __restrict__ fus_w, const float* __restrict__ fus_b,
                            float* __restrict__ h0, int N) {
    __shared__ float swei[128 * 33];
    __shared__ float nwei[128 * 33];
    int tid = threadIdx.x;
    for (int i = tid; i < 128 * 32; i += 256) {
        int r = i >> 5, k = i & 31;
        swei[r * 33 + k] = sat_w[i];
        nwei[r * 33 + k] = neigh_w[i];
    }
    __syncthreads();
    int lane = tid & 63;
    int wv = tid >> 6;
    int nwaves = gridDim.x * 4;
    float sb0 = sat_b[lane], sb1 = sat_b[lane + 64];
    float nb0 = neigh_b[lane], nb1 = neigh_b[lane + 64];
    float fw0 = fus_w[lane], fw1 = fus_w[lane + 64];
    float fw2 = fus_w[128 + lane], fw3 = fus_w[192 + lane];
    float fb = fus_b[0];
    for (int node = blockIdx.x * 4 + wv; node < N; node += nwaves) {
        float xv = x[(size_t)node * 64 + lane];
        float a0 = sb0, a1 = sb1, b0 = nb0, b1 = nb1;
#pragma unroll 8
        for (int k = 0; k < 32; ++k) {
            float xk = __shfl(xv, k);
            a0 += xk * swei[lane * 33 + k];
            a1 += xk * swei[(lane + 64) * 33 + k];
            float yk = __shfl(xv, 32 + k);
            b0 += yk * nwei[lane * 33 + k];
            b1 += yk * nwei[(lane + 64) * 33 + k];
        }
        float s0 = fmaxf(a0, 0.f), s1 = fmaxf(a1, 0.f);
        float n0 = fmaxf(b0, 0.f), n1 = fmaxf(b1, 0.f);
        float part = s0 * fw0 + s1 * fw1 + n0 * fw2 + n1 * fw3;
        for (int off = 32; off; off >>= 1) part += __shfl_xor(part, off);
        float g = 1.f / (1.f + __expf(-(part + fb)));
        h0[(size_t)node * H + lane] = g * s0 + (1.f - g) * n0;
        h0[(size_t)node * H + lane + 64] = g * s1 + (1.f - g) * n1;
    }
}

// ---------------- 128x128 GEMM: contiguous s_load chunks + fused attn logits ----------------
// a_sp/a_dp non-null => also emit al_s/al_d = (out_row . a_s), (out_row . a_d)
__global__ void gemm128(const float* __restrict__ in, const float* __restrict__ w,
                        const float* __restrict__ bias, int do_relu,
                        float* __restrict__ out, int N,
                        const float* __restrict__ a_sp, const float* __restrict__ a_dp,
                        float* __restrict__ al_s, float* __restrict__ al_d) {
    __shared__ float xl[64 * 129];
    __shared__ float reds[4][64];
    __shared__ float redd[4][64];
    int tid = threadIdx.x;
    int base = blockIdx.x * 64;
    for (int i = tid; i < 64 * 128; i += 256) {
        int n = i >> 7, k = i & 127;
        int gn = base + n;
        xl[n * 129 + k] = (gn < N) ? in[(size_t)gn * 128 + k] : 0.f;
    }
    __syncthreads();
    int lane = tid & 63;
    int wv = __builtin_amdgcn_readfirstlane(tid >> 6); // wave-uniform
    int xb = lane * 129;
    float accs[32];
    for (int cb = 0; cb < 4; ++cb) {
        int col0 = wv * 32 + cb * 8;
        const float* w0 = w + (size_t)col0 * 128;
        float acc[8] = {0.f, 0.f, 0.f, 0.f, 0.f, 0.f, 0.f, 0.f};
        for (int kc = 0; kc < 128; kc += 16) {
            float xv[16];
#pragma unroll
            for (int i = 0; i < 16; ++i) xv[i] = xl[xb + kc + i];
#pragma unroll
            for (int j = 0; j < 8; ++j) {
                const float* wr = w0 + j * 128 + kc; // wave-uniform, contiguous 16
#pragma unroll
                for (int i = 0; i < 16; ++i) acc[j] += xv[i] * wr[i];
            }
        }
#pragma unroll
        for (int j = 0; j < 8; ++j) {
            float v = acc[j] + (bias ? bias[col0 + j] : 0.f);
            if (do_relu) v = fmaxf(v, 0.f);
            accs[cb * 8 + j] = v;
        }
    }
    // stage results to LDS, coalesced write
    __syncthreads();
#pragma unroll
    for (int c = 0; c < 32; ++c) xl[xb + wv * 32 + c] = accs[c];
    __syncthreads();
    for (int i = tid; i < 64 * 128; i += 256) {
        int n = i >> 7, k = i & 127;
        int gn = base + n;
        if (gn < N) out[(size_t)gn * H + k] = xl[n * 129 + k];
    }
    // fused attention logits from the LDS-resident output tile
    if (a_sp) {
        int node = tid & 63;
        int part = tid >> 6; // 0..3, k-range [part*32, +32)
        float ps = 0.f, pd = 0.f;
        int kb = part * 32;
        const float* xr = xl + node * 129 + kb;
#pragma unroll
        for (int k = 0; k < 32; ++k) {
            float v = xr[k];
            ps += v * a_sp[kb + k];
            pd += v * a_dp[kb + k];
        }
        reds[part][node] = ps;
        redd[part][node] = pd;
        __syncthreads();
        if (tid < 64) {
            int gn = base + tid;
            if (gn < N) {
                al_s[gn] = reds[0][tid] + reds[1][tid] + reds[2][tid] + reds[3][tid];
                al_d[gn] = redd[0][tid] + redd[1][tid] + redd[2][tid] + redd[3][tid];
            }
        }
    }
}

// ---------------- CSR build (real edges only; self-loops handled in gat_agg) ----------------
#define SCB 256
__global__ void hist_kernel(const int* __restrict__ dst, int* __restrict__ cnt8, int E, int N) {
    int e = blockIdx.x * blockDim.x + threadIdx.x;
    if (e >= E) return;
    int c = blockIdx.x & 7;
    atomicAdd(cnt8 + (size_t)c * N + dst[e], 1);
}

__global__ void scan_a(const int* __restrict__ cnt8, int* __restrict__ nodeoff,
                       int* __restrict__ blocksum, int N) {
    int i = blockIdx.x * SCB + threadIdx.x;
    int tot = 0;
    if (i < N) {
#pragma unroll
        for (int c = 0; c < 8; ++c) tot += cnt8[(size_t)c * N + i];
    }
    __shared__ int tmp[SCB];
    tmp[threadIdx.x] = tot;
    __syncthreads();
    for (int off = 1; off < SCB; off <<= 1) {
        int t = (threadIdx.x >= off) ? tmp[threadIdx.x - off] : 0;
        __syncthreads();
        tmp[threadIdx.x] += t;
        __syncthreads();
    }
    if (i < N) nodeoff[i] = tmp[threadIdx.x] - tot;
    if (threadIdx.x == SCB - 1) blocksum[blockIdx.x] = tmp[SCB - 1];
}

__global__ void scan_b(const int* __restrict__ blocksum, int* __restrict__ blockoff,
                       int* __restrict__ rowptrN, int NB) {
    __shared__ int tmp[1024];
    int t = threadIdx.x;
    int v = (t < NB) ? blocksum[t] : 0;
    tmp[t] = v;
    __syncthreads();
    for (int off = 1; off < 1024; off <<= 1) {
        int u = (t >= off) ? tmp[t - off] : 0;
        __syncthreads();
        tmp[t] += u;
        __syncthreads();
    }
    if (t < NB) blockoff[t] = tmp[t] - v;
    if (t == 1023) *rowptrN = tmp[1023];
}

__global__ void scan_c(int* __restrict__ cnt8, const int* __restrict__ nodeoff,
                       const int* __restrict__ blockoff, int* __restrict__ rowptr, int N) {
    int i = blockIdx.x * SCB + threadIdx.x;
    if (i >= N) return;
    int run = blockoff[blockIdx.x] + nodeoff[i];
    rowptr[i] = run;
#pragma unroll
    for (int c = 0; c < 8; ++c) {
        int v = cnt8[(size_t)c * N + i];
        cnt8[(size_t)c * N + i] = run; // becomes cursor
        run += v;
    }
}

__global__ void scatter_kernel(const int* __restrict__ src, const int* __restrict__ dst,
                               int* __restrict__ cursor8, int* __restrict__ ssrc, int E, int N) {
    int e = blockIdx.x * blockDim.x + threadIdx.x;
    if (e >= E) return;
    int c = blockIdx.x & 7;
    int pos = atomicAdd(cursor8 + (size_t)c * N + dst[e], 1);
    ssrc[pos] = src[e];
}

// ---------------- GAT aggregation: one wave per dst node, self-loop inline ----------------
#define PF 8
__global__ void gat_agg(const int* __restrict__ rowptr, const int* __restrict__ ssrc,
                        const float* __restrict__ al_s, const float* __restrict__ al_d,
                        const float* __restrict__ h, float* __restrict__ out, int N) {
    __shared__ int s_sv[4][64];
    __shared__ float s_ev[4][64];
    int wiw = threadIdx.x >> 6;
    int w = (blockIdx.x * blockDim.x + threadIdx.x) >> 6;
    int lane = threadIdx.x & 63;
    if (w >= N) return;
    int beg = rowptr[w], end = rowptr[w + 1];
    float ald = al_d[w];
    float a_self = al_s[w] + ald;
    a_self = (a_self > 0.f) ? a_self : 0.2f * a_self;
    float m = a_self;
    for (int e = beg + lane; e < end; e += 64) {
        float a = al_s[ssrc[e]] + ald;
        a = (a > 0.f) ? a : 0.2f * a;
        m = fmaxf(m, a);
    }
    for (int off = 32; off; off >>= 1) m = fmaxf(m, __shfl_xor(m, off));
    float ss = 0.f, acc0 = 0.f, acc1 = 0.f;
    for (int base = beg; base < end; base += 64) {
        int nch = min(64, end - base);
        int sv = 0;
        float ev = 0.f;
        if (lane < nch) {
            sv = ssrc[base + lane];
            float a = al_s[sv] + ald;
            a = (a > 0.f) ? a : 0.2f * a;
            ev = __expf(a - m);
        }
        ss += ev;
        s_sv[wiw][lane] = sv;
        s_ev[wiw][lane] = ev;
        for (int j0 = 0; j0 < nch; j0 += PF) {
            int np = min(PF, nch - j0);
            float2 hv[PF];
#pragma unroll
            for (int jj = 0; jj < PF; ++jj) {
                if (jj < np) {
                    int svj = s_sv[wiw][j0 + jj];
                    hv[jj] = *(const float2*)(h + (size_t)svj * H + lane * 2);
                }
            }
#pragma unroll
            for (int jj = 0; jj < PF; ++jj) {
                if (jj < np) {
                    float evj = s_ev[wiw][j0 + jj];
                    acc0 += evj * hv[jj].x;
                    acc1 += evj * hv[jj].y;
                }
            }
        }
    }
    for (int off = 32; off; off >>= 1) ss += __shfl_xor(ss, off);
    // self-loop contribution (uniform across lanes for ss; per-lane for features)
    float ev_self = __expf(a_self - m);
    ss += ev_self;
    float2 hs = *(const float2*)(h + (size_t)w * H + lane * 2);
    acc0 += ev_self * hs.x;
    acc1 += ev_self * hs.y;
    float inv = 1.f / (ss + 1e-16f);
    ((float2*)(out + (size_t)w * H))[lane] = make_float2(acc0 * inv, acc1 * inv);
}

// ---------------- BN stats ----------------
__global__ void bn_stats(const float* __restrict__ y, float* __restrict__ accum, int N) {
    int f = threadIdx.x & 127;
    int half = threadIdx.x >> 7;
    float sum = 0.f, sumsq = 0.f;
    for (int n = blockIdx.x * 2 + half; n < N; n += gridDim.x * 2) {
        float v = y[(size_t)n * H + f];
        sum += v;
        sumsq += v * v;
    }
    __shared__ float ls[2][128], ls2[2][128];
    ls[half][f] = sum;
    ls2[half][f] = sumsq;
    __syncthreads();
    if (half == 0) {
        atomicAdd(accum + f, ls[0][f] + ls[1][f]);
        atomicAdd(accum + 128 + f, ls2[0][f] + ls2[1][f]);
    }
}

// ---------------- BN apply + relu + residual ----------------
__global__ void bn_apply(float* __restrict__ y, const float* __restrict__ accum,
                         const float* __restrict__ g, const float* __restrict__ be,
                         const float* __restrict__ res, int N) {
    int i = blockIdx.x * blockDim.x + threadIdx.x;
    if (i >= N * H) return;
    int f = i & 127;
    float Ninv = 1.f / (float)N;
    float mu = accum[f] * Ninv;
    float var = accum[128 + f] * Ninv - mu * mu;
    float v = (y[i] - mu) * rsqrtf(var + 1e-5f) * g[f] + be[f];
    y[i] = fmaxf(v, 0.f) + res[i];
}

// ---------------- final fc2: LDS-staged rows ----------------
__global__ void fc2_kernel(const float* __restrict__ in, const float* __restrict__ w,
                           const float* __restrict__ b, float* __restrict__ out,
                           int N, int OUT) {
    __shared__ float wsm[16 * 132];
    __shared__ float xs[16][129];
    int tid = threadIdx.x;
    for (int i = tid; i < OUT * H; i += 256) {
        int o = i >> 7, k = i & 127;
        wsm[o * 132 + k] = w[i];
    }
    int nb = blockIdx.x * 16;
    for (int i = tid; i < 16 * 128; i += 256) {
        int n = i >> 7, k = i & 127;
        int gn = nb + n;
        xs[n][k] = (gn < N) ? in[(size_t)gn * H + k] : 0.f;
    }
    __syncthreads();
    int o = tid & 15;
    int nn = tid >> 4;
    int n = nb + nn;
    if (n >= N || o >= OUT) return;
    const float* xr = xs[nn];
    const float* wr = wsm + o * 132;
    float acc = b[o];
#pragma unroll 8
    for (int k = 0; k < H; k += 4) {
        acc += xr[k] * wr[k] + xr[k + 1] * wr[k + 1] + xr[k + 2] * wr[k + 2] + xr[k + 3] * wr[k + 3];
    }
    out[(size_t)n * OUT + o] = acc;
}

// ---------------- launch ----------------

extern "C" void kernel_launch(void* const* d_in, const int* in_sizes, int n_in,
                              void* d_out, int out_size, void* d_ws, size_t ws_size,
                              hipStream_t stream) {
    const float* x       = (const float*)d_in[0];
    const int*   ei      = (const int*)d_in[1];
    const float* sat_w   = (const float*)d_in[2];
    const float* sat_b   = (const float*)d_in[3];
    const float* neigh_w = (const float*)d_in[4];
    const float* neigh_b = (const float*)d_in[5];
    const float* fus_w   = (const float*)d_in[6];
    const float* fus_b   = (const float*)d_in[7];
    const float* w1      = (const float*)d_in[8];
    const float* as1     = (const float*)d_in[9];
    const float* ad1     = (const float*)d_in[10];
    const float* g1      = (const float*)d_in[12];
    const float* be1     = (const float*)d_in[13];
    const float* w2      = (const float*)d_in[14];
    const float* as2     = (const float*)d_in[15];
    const float* ad2     = (const float*)d_in[16];
    const float* g2      = (const float*)d_in[18];
    const float* be2     = (const float*)d_in[19];
    const float* fc1_w   = (const float*)d_in[20];
    const float* fc1_b   = (const float*)d_in[21];
    const float* fc2_w   = (const float*)d_in[22];
    const float* fc2_b   = (const float*)d_in[23];

    int N = in_sizes[0] / 64;
    int E = in_sizes[1] / 2;
    int OUT = in_sizes[23];
    int NB = (N + SCB - 1) / SCB;

    float* ws    = (float*)d_ws;
    float* h0    = ws;                      // N*H
    float* hA    = h0 + (size_t)N * H;      // N*H
    float* agg   = hA + (size_t)N * H;      // N*H
    float* al_s  = agg + (size_t)N * H;     // N
    float* al_d  = al_s + N;                // N
    float* accum = al_d + N;                // 256
    int* rowptr  = (int*)(accum + 256);     // N+1
    int* cnt8    = rowptr + (N + 1);        // 8N (becomes cursor8)
    int* nodeoff = cnt8 + (size_t)8 * N;    // N
    int* blocksum= nodeoff + N;             // NB
    int* blockoff= blocksum + NB;           // NB
    int* ssrc    = blockoff + NB;           // E

    const int* srcp = ei;
    const int* dstp = ei + E;

    dim3 b256(256);
    int gEdge = (E + 255) / 256;
    int gGemm = (N + 63) / 64;
    int gNH = (N * H + 255) / 256;
    int gWaveN = (N + 3) / 4;

    // ---- fuse ----
    fuse_kernel<<<2048, b256, 0, stream>>>(x, sat_w, sat_b, neigh_w, neigh_b, fus_w, fus_b, h0, N);

    // ---- CSR build (shared by both layers; real edges only) ----
    fill_u32<<<(8 * N + 255) / 256, b256, 0, stream>>>((unsigned*)cnt8, 0u, 8 * N);
    hist_kernel<<<gEdge, b256, 0, stream>>>(dstp, cnt8, E, N);
    scan_a<<<NB, SCB, 0, stream>>>(cnt8, nodeoff, blocksum, N);
    scan_b<<<1, 1024, 0, stream>>>(blocksum, blockoff, rowptr + N, NB);
    scan_c<<<NB, SCB, 0, stream>>>(cnt8, nodeoff, blockoff, rowptr, N);
    scatter_kernel<<<gEdge, b256, 0, stream>>>(srcp, dstp, cnt8, ssrc, E, N);

    // ================= GAT layer 1 =================
    gemm128<<<gGemm, b256, 0, stream>>>(h0, w1, nullptr, 0, hA, N, as1, ad1, al_s, al_d);
    fill_u32<<<1, 256, 0, stream>>>((unsigned*)accum, 0u, 256);
    gat_agg<<<gWaveN, b256, 0, stream>>>(rowptr, ssrc, al_s, al_d, hA, agg, N);
    bn_stats<<<512, b256, 0, stream>>>(agg, accum, N);
    bn_apply<<<gNH, b256, 0, stream>>>(agg, accum, g1, be1, h0, N);

    // ================= GAT layer 2 =================
    gemm128<<<gGemm, b256, 0, stream>>>(agg, w2, nullptr, 0, hA, N, as2, ad2, al_s, al_d);
    fill_u32<<<1, 256, 0, stream>>>((unsigned*)accum, 0u, 256);
    gat_agg<<<gWaveN, b256, 0, stream>>>(rowptr, ssrc, al_s, al_d, hA, h0, N);
    bn_stats<<<512, b256, 0, stream>>>(h0, accum, N);
    bn_apply<<<gNH, b256, 0, stream>>>(h0, accum, g2, be2, agg, N);

    // ================= head =================
    gemm128<<<gGemm, b256, 0, stream>>>(h0, fc1_w, fc1_b, 1, hA, N, nullptr, nullptr, nullptr, nullptr);
    fc2_kernel<<<(N + 15) / 16, b256, 0, stream>>>(hA, fc2_w, fc2_b, (float*)d_out, N, OUT);
}

// Round 7
// 771.367 us; speedup vs baseline: 1.0515x; 1.0515x over previous
//
#include <hip/hip_runtime.h>

#define H 128

__global__ void fill_u32(unsigned* __restrict__ p, unsigned v, int n) {
    int i = blockIdx.x * blockDim.x + threadIdx.x;
    if (i < n) p[i] = v;
}

// ---------------- fuse: one wave per node, weights in padded LDS ----------------
__global__ void fuse_kernel(const float* __restrict__ x,
                            const float* __restrict__ sat_w, const float* __restrict__ sat_b,
                            const float* __restrict__ neigh_w, const float* __restrict__ neigh_b,
                            const float* __restrict__ fus_w, const float* __restrict__ fus_b,
                            float* __restrict__ h0, int N) {
    __shared__ float swei[128 * 33];
    __shared__ float nwei[128 * 33];
    int tid = threadIdx.x;
    for (int i = tid; i < 128 * 32; i += 256) {
        int r = i >> 5, k = i & 31;
        swei[r * 33 + k] = sat_w[i];
        nwei[r * 33 + k] = neigh_w[i];
    }
    __syncthreads();
    int lane = tid & 63;
    int wv = tid >> 6;
    int nwaves = gridDim.x * 4;
    float sb0 = sat_b[lane], sb1 = sat_b[lane + 64];
    float nb0 = neigh_b[lane], nb1 = neigh_b[lane + 64];
    float fw0 = fus_w[lane], fw1 = fus_w[lane + 64];
    float fw2 = fus_w[128 + lane], fw3 = fus_w[192 + lane];
    float fb = fus_b[0];
    for (int node = blockIdx.x * 4 + wv; node < N; node += nwaves) {
        float xv = x[(size_t)node * 64 + lane];
        float a0 = sb0, a1 = sb1, b0 = nb0, b1 = nb1;
#pragma unroll 8
        for (int k = 0; k < 32; ++k) {
            float xk = __shfl(xv, k);
            a0 += xk * swei[lane * 33 + k];
            a1 += xk * swei[(lane + 64) * 33 + k];
            float yk = __shfl(xv, 32 + k);
            b0 += yk * nwei[lane * 33 + k];
            b1 += yk * nwei[(lane + 64) * 33 + k];
        }
        float s0 = fmaxf(a0, 0.f), s1 = fmaxf(a1, 0.f);
        float n0 = fmaxf(b0, 0.f), n1 = fmaxf(b1, 0.f);
        float part = s0 * fw0 + s1 * fw1 + n0 * fw2 + n1 * fw3;
        for (int off = 32; off; off >>= 1) part += __shfl_xor(part, off);
        float g = 1.f / (1.f + __expf(-(part + fb)));
        h0[(size_t)node * H + lane] = g * s0 + (1.f - g) * n0;
        h0[(size_t)node * H + lane + 64] = g * s1 + (1.f - g) * n1;
    }
}

// ---------------- 128x128 GEMM (tagged) + fused attn logits ----------------
template <int TAG>
__global__ void gemm128(const float* __restrict__ in, const float* __restrict__ w,
                        const float* __restrict__ bias, int do_relu,
                        float* __restrict__ out, int N,
                        const float* __restrict__ a_sp, const float* __restrict__ a_dp,
                        float* __restrict__ al_s, float* __restrict__ al_d) {
    __shared__ float xl[64 * 129];
    __shared__ float reds[4][64];
    __shared__ float redd[4][64];
    int tid = threadIdx.x;
    int base = blockIdx.x * 64;
    for (int i = tid; i < 64 * 128; i += 256) {
        int n = i >> 7, k = i & 127;
        int gn = base + n;
        xl[n * 129 + k] = (gn < N) ? in[(size_t)gn * 128 + k] : 0.f;
    }
    __syncthreads();
    int lane = tid & 63;
    int wv = __builtin_amdgcn_readfirstlane(tid >> 6);
    int xb = lane * 129;
    float accs[32];
    for (int cb = 0; cb < 4; ++cb) {
        int col0 = wv * 32 + cb * 8;
        const float* w0 = w + (size_t)col0 * 128;
        float acc[8] = {0.f, 0.f, 0.f, 0.f, 0.f, 0.f, 0.f, 0.f};
        for (int kc = 0; kc < 128; kc += 16) {
            float xv[16];
#pragma unroll
            for (int i = 0; i < 16; ++i) xv[i] = xl[xb + kc + i];
#pragma unroll
            for (int j = 0; j < 8; ++j) {
                const float* wr = w0 + j * 128 + kc;
#pragma unroll
                for (int i = 0; i < 16; ++i) acc[j] += xv[i] * wr[i];
            }
        }
#pragma unroll
        for (int j = 0; j < 8; ++j) {
            float v = acc[j] + (bias ? bias[col0 + j] : 0.f);
            if (do_relu) v = fmaxf(v, 0.f);
            accs[cb * 8 + j] = v;
        }
    }
    __syncthreads();
#pragma unroll
    for (int c = 0; c < 32; ++c) xl[xb + wv * 32 + c] = accs[c];
    __syncthreads();
    for (int i = tid; i < 64 * 128; i += 256) {
        int n = i >> 7, k = i & 127;
        int gn = base + n;
        if (gn < N) out[(size_t)gn * H + k] = xl[n * 129 + k];
    }
    if (a_sp) {
        int node = tid & 63;
        int part = tid >> 6;
        float ps = 0.f, pd = 0.f;
        int kb = part * 32;
        const float* xr = xl + node * 129 + kb;
#pragma unroll
        for (int k = 0; k < 32; ++k) {
            float v = xr[k];
            ps += v * a_sp[kb + k];
            pd += v * a_dp[kb + k];
        }
        reds[part][node] = ps;
        redd[part][node] = pd;
        __syncthreads();
        if (tid < 64) {
            int gn = base + tid;
            if (gn < N) {
                al_s[gn] = reds[0][tid] + reds[1][tid] + reds[2][tid] + reds[3][tid];
                al_d[gn] = redd[0][tid] + redd[1][tid] + redd[2][tid] + redd[3][tid];
            }
        }
    }
}

// ---------------- CSR build with XCD-ownership (dst-range per block-group) ----------------
#define SCB 256
// group g = blockIdx&7 owns dst range [g*NR, min((g+1)*NR,N)); all groups scan all edges.
__global__ void hist8(const int* __restrict__ dst, int* __restrict__ cnt, int E, int N) {
    int g = blockIdx.x & 7;
    int chunk = blockIdx.x >> 3;
    int nch = gridDim.x >> 3;
    int NR = (N + 7) >> 3;
    int lo = g * NR;
    int hi = min(lo + NR, N);
    for (int e = chunk * SCB + threadIdx.x; e < E; e += nch * SCB) {
        int d = dst[e];
        if (d >= lo && d < hi) atomicAdd(cnt + d, 1);
    }
}

__global__ void scan_a(const int* __restrict__ cnt, int* __restrict__ nodeoff,
                       int* __restrict__ blocksum, int N) {
    int i = blockIdx.x * SCB + threadIdx.x;
    int tot = (i < N) ? cnt[i] : 0;
    __shared__ int tmp[SCB];
    tmp[threadIdx.x] = tot;
    __syncthreads();
    for (int off = 1; off < SCB; off <<= 1) {
        int t = (threadIdx.x >= off) ? tmp[threadIdx.x - off] : 0;
        __syncthreads();
        tmp[threadIdx.x] += t;
        __syncthreads();
    }
    if (i < N) nodeoff[i] = tmp[threadIdx.x] - tot;
    if (threadIdx.x == SCB - 1) blocksum[blockIdx.x] = tmp[SCB - 1];
}

__global__ void scan_b(const int* __restrict__ blocksum, int* __restrict__ blockoff,
                       int* __restrict__ rowptrN, int NB) {
    __shared__ int tmp[1024];
    int t = threadIdx.x;
    int v = (t < NB) ? blocksum[t] : 0;
    tmp[t] = v;
    __syncthreads();
    for (int off = 1; off < 1024; off <<= 1) {
        int u = (t >= off) ? tmp[t - off] : 0;
        __syncthreads();
        tmp[t] += u;
        __syncthreads();
    }
    if (t < NB) blockoff[t] = tmp[t] - v;
    if (t == 1023) *rowptrN = tmp[1023];
}

__global__ void scan_c(const int* __restrict__ nodeoff, const int* __restrict__ blockoff,
                       int* __restrict__ rowptr, int* __restrict__ cursor, int N) {
    int i = blockIdx.x * SCB + threadIdx.x;
    if (i >= N) return;
    int run = blockoff[blockIdx.x] + nodeoff[i];
    rowptr[i] = run;
    cursor[i] = run;
}

__global__ void scatter8(const int* __restrict__ src, const int* __restrict__ dst,
                         int* __restrict__ cursor, int* __restrict__ ssrc, int E, int N) {
    int g = blockIdx.x & 7;
    int chunk = blockIdx.x >> 3;
    int nch = gridDim.x >> 3;
    int NR = (N + 7) >> 3;
    int lo = g * NR;
    int hi = min(lo + NR, N);
    for (int e = chunk * SCB + threadIdx.x; e < E; e += nch * SCB) {
        int d = dst[e];
        if (d >= lo && d < hi) {
            int pos = atomicAdd(cursor + d, 1);
            ssrc[pos] = src[e];
        }
    }
}

// ---------------- GAT aggregation (tagged): one wave per dst node ----------------
#define PF 8
template <int TAG>
__global__ void gat_agg(const int* __restrict__ rowptr, const int* __restrict__ ssrc,
                        const float* __restrict__ al_s, const float* __restrict__ al_d,
                        const float* __restrict__ h, float* __restrict__ out, int N) {
    __shared__ int s_sv[4][64];
    __shared__ float s_ev[4][64];
    int wiw = threadIdx.x >> 6;
    int w = (blockIdx.x * blockDim.x + threadIdx.x) >> 6;
    int lane = threadIdx.x & 63;
    if (w >= N) return;
    int beg = rowptr[w], end = rowptr[w + 1];
    float ald = al_d[w];
    float a_self = al_s[w] + ald;
    a_self = (a_self > 0.f) ? a_self : 0.2f * a_self;
    float m = a_self;
    for (int e = beg + lane; e < end; e += 64) {
        float a = al_s[ssrc[e]] + ald;
        a = (a > 0.f) ? a : 0.2f * a;
        m = fmaxf(m, a);
    }
    for (int off = 32; off; off >>= 1) m = fmaxf(m, __shfl_xor(m, off));
    float ss = 0.f, acc0 = 0.f, acc1 = 0.f;
    for (int base = beg; base < end; base += 64) {
        int nch = min(64, end - base);
        int sv = 0;
        float ev = 0.f;
        if (lane < nch) {
            sv = ssrc[base + lane];
            float a = al_s[sv] + ald;
            a = (a > 0.f) ? a : 0.2f * a;
            ev = __expf(a - m);
        }
        ss += ev;
        s_sv[wiw][lane] = sv;
        s_ev[wiw][lane] = ev;
        for (int j0 = 0; j0 < nch; j0 += PF) {
            int np = min(PF, nch - j0);
            float2 hv[PF];
#pragma unroll
            for (int jj = 0; jj < PF; ++jj) {
                if (jj < np) {
                    int svj = s_sv[wiw][j0 + jj];
                    hv[jj] = *(const float2*)(h + (size_t)svj * H + lane * 2);
                }
            }
#pragma unroll
            for (int jj = 0; jj < PF; ++jj) {
                if (jj < np) {
                    float evj = s_ev[wiw][j0 + jj];
                    acc0 += evj * hv[jj].x;
                    acc1 += evj * hv[jj].y;
                }
            }
        }
    }
    for (int off = 32; off; off >>= 1) ss += __shfl_xor(ss, off);
    float ev_self = __expf(a_self - m);
    ss += ev_self;
    float2 hs = *(const float2*)(h + (size_t)w * H + lane * 2);
    acc0 += ev_self * hs.x;
    acc1 += ev_self * hs.y;
    float inv = 1.f / (ss + 1e-16f);
    ((float2*)(out + (size_t)w * H))[lane] = make_float2(acc0 * inv, acc1 * inv);
}

// ---------------- BN stats ----------------
__global__ void bn_stats(const float* __restrict__ y, float* __restrict__ accum, int N) {
    int f = threadIdx.x & 127;
    int half = threadIdx.x >> 7;
    float sum = 0.f, sumsq = 0.f;
    for (int n = blockIdx.x * 2 + half; n < N; n += gridDim.x * 2) {
        float v = y[(size_t)n * H + f];
        sum += v;
        sumsq += v * v;
    }
    __shared__ float ls[2][128], ls2[2][128];
    ls[half][f] = sum;
    ls2[half][f] = sumsq;
    __syncthreads();
    if (half == 0) {
        atomicAdd(accum + f, ls[0][f] + ls[1][f]);
        atomicAdd(accum + 128 + f, ls2[0][f] + ls2[1][f]);
    }
}

// ---------------- BN apply + relu + residual ----------------
__global__ void bn_apply(float* __restrict__ y, const float* __restrict__ accum,
                         const float* __restrict__ g, const float* __restrict__ be,
                         const float* __restrict__ res, int N) {
    int i = blockIdx.x * blockDim.x + threadIdx.x;
    if (i >= N * H) return;
    int f = i & 127;
    float Ninv = 1.f / (float)N;
    float mu = accum[f] * Ninv;
    float var = accum[128 + f] * Ninv - mu * mu;
    float v = (y[i] - mu) * rsqrtf(var + 1e-5f) * g[f] + be[f];
    y[i] = fmaxf(v, 0.f) + res[i];
}

// ---------------- final fc2: LDS-staged rows ----------------
__global__ void fc2_kernel(const float* __restrict__ in, const float* __restrict__ w,
                           const float* __restrict__ b, float* __restrict__ out,
                           int N, int OUT) {
    __shared__ float wsm[16 * 132];
    __shared__ float xs[16][129];
    int tid = threadIdx.x;
    for (int i = tid; i < OUT * H; i += 256) {
        int o = i >> 7, k = i & 127;
        wsm[o * 132 + k] = w[i];
    }
    int nb = blockIdx.x * 16;
    for (int i = tid; i < 16 * 128; i += 256) {
        int n = i >> 7, k = i & 127;
        int gn = nb + n;
        xs[n][k] = (gn < N) ? in[(size_t)gn * H + k] : 0.f;
    }
    __syncthreads();
    int o = tid & 15;
    int nn = tid >> 4;
    int n = nb + nn;
    if (n >= N || o >= OUT) return;
    const float* xr = xs[nn];
    const float* wr = wsm + o * 132;
    float acc = b[o];
#pragma unroll 8
    for (int k = 0; k < H; k += 4) {
        acc += xr[k] * wr[k] + xr[k + 1] * wr[k + 1] + xr[k + 2] * wr[k + 2] + xr[k + 3] * wr[k + 3];
    }
    out[(size_t)n * OUT + o] = acc;
}

// ---------------- launch ----------------

extern "C" void kernel_launch(void* const* d_in, const int* in_sizes, int n_in,
                              void* d_out, int out_size, void* d_ws, size_t ws_size,
                              hipStream_t stream) {
    const float* x       = (const float*)d_in[0];
    const int*   ei      = (const int*)d_in[1];
    const float* sat_w   = (const float*)d_in[2];
    const float* sat_b   = (const float*)d_in[3];
    const float* neigh_w = (const float*)d_in[4];
    const float* neigh_b = (const float*)d_in[5];
    const float* fus_w   = (const float*)d_in[6];
    const float* fus_b   = (const float*)d_in[7];
    const float* w1      = (const float*)d_in[8];
    const float* as1     = (const float*)d_in[9];
    const float* ad1     = (const float*)d_in[10];
    const float* g1      = (const float*)d_in[12];
    const float* be1     = (const float*)d_in[13];
    const float* w2      = (const float*)d_in[14];
    const float* as2     = (const float*)d_in[15];
    const float* ad2     = (const float*)d_in[16];
    const float* g2      = (const float*)d_in[18];
    const float* be2     = (const float*)d_in[19];
    const float* fc1_w   = (const float*)d_in[20];
    const float* fc1_b   = (const float*)d_in[21];
    const float* fc2_w   = (const float*)d_in[22];
    const float* fc2_b   = (const float*)d_in[23];

    int N = in_sizes[0] / 64;
    int E = in_sizes[1] / 2;
    int OUT = in_sizes[23];
    int NB = (N + SCB - 1) / SCB;

    float* ws    = (float*)d_ws;
    float* h0    = ws;                      // N*H
    float* hA    = h0 + (size_t)N * H;      // N*H
    float* agg   = hA + (size_t)N * H;      // N*H
    float* al_s  = agg + (size_t)N * H;     // N
    float* al_d  = al_s + N;                // N
    float* accum = al_d + N;                // 256
    int* rowptr  = (int*)(accum + 256);     // N+1
    int* cnt     = rowptr + (N + 1);        // N
    int* cursor  = cnt + N;                 // N
    int* nodeoff = cursor + N;              // N
    int* blocksum= nodeoff + N;             // NB
    int* blockoff= blocksum + NB;           // NB
    int* ssrc    = blockoff + NB;           // E

    const int* srcp = ei;
    const int* dstp = ei + E;

    dim3 b256(256);
    int gGemm = (N + 63) / 64;
    int gNH = (N * H + 255) / 256;
    int gWaveN = (N + 3) / 4;
    int gOwn = 512 * 8; // 512 chunks x 8 ownership groups

    // ---- fuse ----
    fuse_kernel<<<2048, b256, 0, stream>>>(x, sat_w, sat_b, neigh_w, neigh_b, fus_w, fus_b, h0, N);

    // ---- CSR build (XCD-ownership; real edges only) ----
    fill_u32<<<(N + 255) / 256, b256, 0, stream>>>((unsigned*)cnt, 0u, N);
    hist8<<<gOwn, b256, 0, stream>>>(dstp, cnt, E, N);
    scan_a<<<NB, SCB, 0, stream>>>(cnt, nodeoff, blocksum, N);
    scan_b<<<1, 1024, 0, stream>>>(blocksum, blockoff, rowptr + N, NB);
    scan_c<<<NB, SCB, 0, stream>>>(nodeoff, blockoff, rowptr, cursor, N);
    scatter8<<<gOwn, b256, 0, stream>>>(srcp, dstp, cursor, ssrc, E, N);

    // ================= GAT layer 1 =================
    gemm128<1><<<gGemm, b256, 0, stream>>>(h0, w1, nullptr, 0, hA, N, as1, ad1, al_s, al_d);
    fill_u32<<<1, 256, 0, stream>>>((unsigned*)accum, 0u, 256);
    gat_agg<1><<<gWaveN, b256, 0, stream>>>(rowptr, ssrc, al_s, al_d, hA, agg, N);
    bn_stats<<<512, b256, 0, stream>>>(agg, accum, N);
    bn_apply<<<gNH, b256, 0, stream>>>(agg, accum, g1, be1, h0, N);

    // ================= GAT layer 2 =================
    gemm128<2><<<gGemm, b256, 0, stream>>>(agg, w2, nullptr, 0, hA, N, as2, ad2, al_s, al_d);
    fill_u32<<<1, 256, 0, stream>>>((unsigned*)accum, 0u, 256);
    gat_agg<2><<<gWaveN, b256, 0, stream>>>(rowptr, ssrc, al_s, al_d, hA, h0, N);
    bn_stats<<<512, b256, 0, stream>>>(h0, accum, N);
    bn_apply<<<gNH, b256, 0, stream>>>(h0, accum, g2, be2, agg, N);

    // ================= head =================
    gemm128<3><<<gGemm, b256, 0, stream>>>(h0, fc1_w, fc1_b, 1, hA, N, nullptr, nullptr, nullptr, nullptr);
    fc2_kernel<<<(N + 15) / 16, b256, 0, stream>>>(hA, fc2_w, fc2_b, (float*)d_out, N, OUT);
}

// Round 8
// 641.199 us; speedup vs baseline: 1.2649x; 1.2030x over previous
//
#include <hip/hip_runtime.h>

#define H 128

__device__ __forceinline__ float bf2f(unsigned short u) {
    return __uint_as_float(((unsigned)u) << 16);
}
__device__ __forceinline__ unsigned short f2bf(float f) {
    unsigned u = __float_as_uint(f);
    unsigned r = (u + 0x7fffu + ((u >> 16) & 1u)) >> 16;
    return (unsigned short)r;
}

__global__ void fill_u32(unsigned* __restrict__ p, unsigned v, int n) {
    int i = blockIdx.x * blockDim.x + threadIdx.x;
    if (i < n) p[i] = v;
}

// ---------------- fuse: one wave per node, weights in padded LDS ----------------
__global__ void fuse_kernel(const float* __restrict__ x,
                            const float* __restrict__ sat_w, const float* __restrict__ sat_b,
                            const float* __restrict__ neigh_w, const float* __restrict__ neigh_b,
                            const float* __restrict__ fus_w, const float* __restrict__ fus_b,
                            float* __restrict__ h0, int N) {
    __shared__ float swei[128 * 33];
    __shared__ float nwei[128 * 33];
    int tid = threadIdx.x;
    for (int i = tid; i < 128 * 32; i += 256) {
        int r = i >> 5, k = i & 31;
        swei[r * 33 + k] = sat_w[i];
        nwei[r * 33 + k] = neigh_w[i];
    }
    __syncthreads();
    int lane = tid & 63;
    int wv = tid >> 6;
    int nwaves = gridDim.x * 4;
    float sb0 = sat_b[lane], sb1 = sat_b[lane + 64];
    float nb0 = neigh_b[lane], nb1 = neigh_b[lane + 64];
    float fw0 = fus_w[lane], fw1 = fus_w[lane + 64];
    float fw2 = fus_w[128 + lane], fw3 = fus_w[192 + lane];
    float fb = fus_b[0];
    for (int node = blockIdx.x * 4 + wv; node < N; node += nwaves) {
        float xv = x[(size_t)node * 64 + lane];
        float a0 = sb0, a1 = sb1, b0 = nb0, b1 = nb1;
#pragma unroll 8
        for (int k = 0; k < 32; ++k) {
            float xk = __shfl(xv, k);
            a0 += xk * swei[lane * 33 + k];
            a1 += xk * swei[(lane + 64) * 33 + k];
            float yk = __shfl(xv, 32 + k);
            b0 += yk * nwei[lane * 33 + k];
            b1 += yk * nwei[(lane + 64) * 33 + k];
        }
        float s0 = fmaxf(a0, 0.f), s1 = fmaxf(a1, 0.f);
        float n0 = fmaxf(b0, 0.f), n1 = fmaxf(b1, 0.f);
        float part = s0 * fw0 + s1 * fw1 + n0 * fw2 + n1 * fw3;
        for (int off = 32; off; off >>= 1) part += __shfl_xor(part, off);
        float g = 1.f / (1.f + __expf(-(part + fb)));
        h0[(size_t)node * H + lane] = g * s0 + (1.f - g) * n0;
        h0[(size_t)node * H + lane + 64] = g * s1 + (1.f - g) * n1;
    }
}

// ---------------- 128x128 GEMM (tagged) + fused attn logits; optional bf16 out ----------------
template <int TAG, int OBF16>
__global__ void gemm128(const float* __restrict__ in, const float* __restrict__ w,
                        const float* __restrict__ bias, int do_relu,
                        void* __restrict__ outv, int N,
                        const float* __restrict__ a_sp, const float* __restrict__ a_dp,
                        float* __restrict__ al_s, float* __restrict__ al_d) {
    __shared__ float xl[64 * 129];
    __shared__ float reds[4][64];
    __shared__ float redd[4][64];
    int tid = threadIdx.x;
    int base = blockIdx.x * 64;
    for (int i = tid; i < 64 * 128; i += 256) {
        int n = i >> 7, k = i & 127;
        int gn = base + n;
        xl[n * 129 + k] = (gn < N) ? in[(size_t)gn * 128 + k] : 0.f;
    }
    __syncthreads();
    int lane = tid & 63;
    int wv = __builtin_amdgcn_readfirstlane(tid >> 6);
    int xb = lane * 129;
    float accs[32];
    for (int cb = 0; cb < 4; ++cb) {
        int col0 = wv * 32 + cb * 8;
        const float* w0 = w + (size_t)col0 * 128;
        float acc[8] = {0.f, 0.f, 0.f, 0.f, 0.f, 0.f, 0.f, 0.f};
        for (int kc = 0; kc < 128; kc += 16) {
            float xv[16];
#pragma unroll
            for (int i = 0; i < 16; ++i) xv[i] = xl[xb + kc + i];
#pragma unroll
            for (int j = 0; j < 8; ++j) {
                const float* wr = w0 + j * 128 + kc;
#pragma unroll
                for (int i = 0; i < 16; ++i) acc[j] += xv[i] * wr[i];
            }
        }
#pragma unroll
        for (int j = 0; j < 8; ++j) {
            float v = acc[j] + (bias ? bias[col0 + j] : 0.f);
            if (do_relu) v = fmaxf(v, 0.f);
            accs[cb * 8 + j] = v;
        }
    }
    __syncthreads();
#pragma unroll
    for (int c = 0; c < 32; ++c) xl[xb + wv * 32 + c] = accs[c];
    __syncthreads();
    for (int i = tid; i < 64 * 128; i += 256) {
        int n = i >> 7, k = i & 127;
        int gn = base + n;
        if (gn < N) {
            if (OBF16) ((unsigned short*)outv)[(size_t)gn * H + k] = f2bf(xl[n * 129 + k]);
            else       ((float*)outv)[(size_t)gn * H + k] = xl[n * 129 + k];
        }
    }
    if (a_sp) {
        int node = tid & 63;
        int part = tid >> 6;
        float ps = 0.f, pd = 0.f;
        int kb = part * 32;
        const float* xr = xl + node * 129 + kb;
#pragma unroll
        for (int k = 0; k < 32; ++k) {
            float v = xr[k];
            ps += v * a_sp[kb + k];
            pd += v * a_dp[kb + k];
        }
        reds[part][node] = ps;
        redd[part][node] = pd;
        __syncthreads();
        if (tid < 64) {
            int gn = base + tid;
            if (gn < N) {
                al_s[gn] = reds[0][tid] + reds[1][tid] + reds[2][tid] + reds[3][tid];
                al_d[gn] = redd[0][tid] + redd[1][tid] + redd[2][tid] + redd[3][tid];
            }
        }
    }
}

// ---------------- CSR build with XCD-ownership ----------------
#define SCB 256
__global__ void hist8(const int* __restrict__ dst, int* __restrict__ cnt, int E, int N) {
    int g = blockIdx.x & 7;
    int chunk = blockIdx.x >> 3;
    int nch = gridDim.x >> 3;
    int NR = (N + 7) >> 3;
    int lo = g * NR;
    int hi = min(lo + NR, N);
    for (int e = chunk * SCB + threadIdx.x; e < E; e += nch * SCB) {
        int d = dst[e];
        if (d >= lo && d < hi) atomicAdd(cnt + d, 1);
    }
}

__global__ void scan_a(const int* __restrict__ cnt, int* __restrict__ nodeoff,
                       int* __restrict__ blocksum, int N) {
    int i = blockIdx.x * SCB + threadIdx.x;
    int tot = (i < N) ? cnt[i] : 0;
    __shared__ int tmp[SCB];
    tmp[threadIdx.x] = tot;
    __syncthreads();
    for (int off = 1; off < SCB; off <<= 1) {
        int t = (threadIdx.x >= off) ? tmp[threadIdx.x - off] : 0;
        __syncthreads();
        tmp[threadIdx.x] += t;
        __syncthreads();
    }
    if (i < N) nodeoff[i] = tmp[threadIdx.x] - tot;
    if (threadIdx.x == SCB - 1) blocksum[blockIdx.x] = tmp[SCB - 1];
}

__global__ void scan_b(const int* __restrict__ blocksum, int* __restrict__ blockoff,
                       int* __restrict__ rowptrN, int NB) {
    __shared__ int tmp[1024];
    int t = threadIdx.x;
    int v = (t < NB) ? blocksum[t] : 0;
    tmp[t] = v;
    __syncthreads();
    for (int off = 1; off < 1024; off <<= 1) {
        int u = (t >= off) ? tmp[t - off] : 0;
        __syncthreads();
        tmp[t] += u;
        __syncthreads();
    }
    if (t < NB) blockoff[t] = tmp[t] - v;
    if (t == 1023) *rowptrN = tmp[1023];
}

// also zeroes the two BN accumulators (512 floats)
__global__ void scan_c(const int* __restrict__ nodeoff, const int* __restrict__ blockoff,
                       int* __restrict__ rowptr, int* __restrict__ cursor,
                       float* __restrict__ accum2, int N) {
    if (blockIdx.x < 2) {
        accum2[blockIdx.x * 256 + threadIdx.x] = 0.f;
    }
    int i = blockIdx.x * SCB + threadIdx.x;
    if (i >= N) return;
    int run = blockoff[blockIdx.x] + nodeoff[i];
    rowptr[i] = run;
    cursor[i] = run;
}

__global__ void scatter8(const int* __restrict__ src, const int* __restrict__ dst,
                         int* __restrict__ cursor, int* __restrict__ ssrc, int E, int N) {
    int g = blockIdx.x & 7;
    int chunk = blockIdx.x >> 3;
    int nch = gridDim.x >> 3;
    int NR = (N + 7) >> 3;
    int lo = g * NR;
    int hi = min(lo + NR, N);
    for (int e = chunk * SCB + threadIdx.x; e < E; e += nch * SCB) {
        int d = dst[e];
        if (d >= lo && d < hi) {
            int pos = atomicAdd(cursor + d, 1);
            ssrc[pos] = src[e];
        }
    }
}

// ---------------- GAT aggregation (tagged): one wave per dst node, bf16 h ----------------
#define PF 8
template <int TAG>
__global__ void gat_agg(const int* __restrict__ rowptr, const int* __restrict__ ssrc,
                        const float* __restrict__ al_s, const float* __restrict__ al_d,
                        const unsigned short* __restrict__ hb, float* __restrict__ out, int N) {
    __shared__ int s_sv[4][64];
    __shared__ float s_ev[4][64];
    int wiw = threadIdx.x >> 6;
    int w = (blockIdx.x * blockDim.x + threadIdx.x) >> 6;
    int lane = threadIdx.x & 63;
    if (w >= N) return;
    int beg = rowptr[w], end = rowptr[w + 1];
    float ald = al_d[w];
    float a_self = al_s[w] + ald;
    a_self = (a_self > 0.f) ? a_self : 0.2f * a_self;
    float m = a_self;
    for (int e = beg + lane; e < end; e += 64) {
        float a = al_s[ssrc[e]] + ald;
        a = (a > 0.f) ? a : 0.2f * a;
        m = fmaxf(m, a);
    }
    for (int off = 32; off; off >>= 1) m = fmaxf(m, __shfl_xor(m, off));
    float ss = 0.f, acc0 = 0.f, acc1 = 0.f;
    for (int base = beg; base < end; base += 64) {
        int nch = min(64, end - base);
        int sv = 0;
        float ev = 0.f;
        if (lane < nch) {
            sv = ssrc[base + lane];
            float a = al_s[sv] + ald;
            a = (a > 0.f) ? a : 0.2f * a;
            ev = __expf(a - m);
        }
        ss += ev;
        s_sv[wiw][lane] = sv;
        s_ev[wiw][lane] = ev;
        for (int j0 = 0; j0 < nch; j0 += PF) {
            int np = min(PF, nch - j0);
            ushort2 hv[PF];
#pragma unroll
            for (int jj = 0; jj < PF; ++jj) {
                if (jj < np) {
                    int svj = s_sv[wiw][j0 + jj];
                    hv[jj] = ((const ushort2*)(hb + (size_t)svj * H))[lane];
                }
            }
#pragma unroll
            for (int jj = 0; jj < PF; ++jj) {
                if (jj < np) {
                    float evj = s_ev[wiw][j0 + jj];
                    acc0 += evj * bf2f(hv[jj].x);
                    acc1 += evj * bf2f(hv[jj].y);
                }
            }
        }
    }
    for (int off = 32; off; off >>= 1) ss += __shfl_xor(ss, off);
    float ev_self = __expf(a_self - m);
    ss += ev_self;
    ushort2 hs = ((const ushort2*)(hb + (size_t)w * H))[lane];
    acc0 += ev_self * bf2f(hs.x);
    acc1 += ev_self * bf2f(hs.y);
    float inv = 1.f / (ss + 1e-16f);
    ((float2*)(out + (size_t)w * H))[lane] = make_float2(acc0 * inv, acc1 * inv);
}

// ---------------- BN stats ----------------
__global__ void bn_stats(const float* __restrict__ y, float* __restrict__ accum, int N) {
    int f = threadIdx.x & 127;
    int half = threadIdx.x >> 7;
    float sum = 0.f, sumsq = 0.f;
    for (int n = blockIdx.x * 2 + half; n < N; n += gridDim.x * 2) {
        float v = y[(size_t)n * H + f];
        sum += v;
        sumsq += v * v;
    }
    __shared__ float ls[2][128], ls2[2][128];
    ls[half][f] = sum;
    ls2[half][f] = sumsq;
    __syncthreads();
    if (half == 0) {
        atomicAdd(accum + f, ls[0][f] + ls[1][f]);
        atomicAdd(accum + 128 + f, ls2[0][f] + ls2[1][f]);
    }
}

// ---------------- BN apply + relu + residual ----------------
__global__ void bn_apply(float* __restrict__ y, const float* __restrict__ accum,
                         const float* __restrict__ g, const float* __restrict__ be,
                         const float* __restrict__ res, int N) {
    int i = blockIdx.x * blockDim.x + threadIdx.x;
    if (i >= N * H) return;
    int f = i & 127;
    float Ninv = 1.f / (float)N;
    float mu = accum[f] * Ninv;
    float var = accum[128 + f] * Ninv - mu * mu;
    float v = (y[i] - mu) * rsqrtf(var + 1e-5f) * g[f] + be[f];
    y[i] = fmaxf(v, 0.f) + res[i];
}

// ---------------- final fc2: LDS-staged rows ----------------
__global__ void fc2_kernel(const float* __restrict__ in, const float* __restrict__ w,
                           const float* __restrict__ b, float* __restrict__ out,
                           int N, int OUT) {
    __shared__ float wsm[16 * 132];
    __shared__ float xs[16][129];
    int tid = threadIdx.x;
    for (int i = tid; i < OUT * H; i += 256) {
        int o = i >> 7, k = i & 127;
        wsm[o * 132 + k] = w[i];
    }
    int nb = blockIdx.x * 16;
    for (int i = tid; i < 16 * 128; i += 256) {
        int n = i >> 7, k = i & 127;
        int gn = nb + n;
        xs[n][k] = (gn < N) ? in[(size_t)gn * H + k] : 0.f;
    }
    __syncthreads();
    int o = tid & 15;
    int nn = tid >> 4;
    int n = nb + nn;
    if (n >= N || o >= OUT) return;
    const float* xr = xs[nn];
    const float* wr = wsm + o * 132;
    float acc = b[o];
#pragma unroll 8
    for (int k = 0; k < H; k += 4) {
        acc += xr[k] * wr[k] + xr[k + 1] * wr[k + 1] + xr[k + 2] * wr[k + 2] + xr[k + 3] * wr[k + 3];
    }
    out[(size_t)n * OUT + o] = acc;
}

// ---------------- launch ----------------

extern "C" void kernel_launch(void* const* d_in, const int* in_sizes, int n_in,
                              void* d_out, int out_size, void* d_ws, size_t ws_size,
                              hipStream_t stream) {
    const float* x       = (const float*)d_in[0];
    const int*   ei      = (const int*)d_in[1];
    const float* sat_w   = (const float*)d_in[2];
    const float* sat_b   = (const float*)d_in[3];
    const float* neigh_w = (const float*)d_in[4];
    const float* neigh_b = (const float*)d_in[5];
    const float* fus_w   = (const float*)d_in[6];
    const float* fus_b   = (const float*)d_in[7];
    const float* w1      = (const float*)d_in[8];
    const float* as1     = (const float*)d_in[9];
    const float* ad1     = (const float*)d_in[10];
    const float* g1      = (const float*)d_in[12];
    const float* be1     = (const float*)d_in[13];
    const float* w2      = (const float*)d_in[14];
    const float* as2     = (const float*)d_in[15];
    const float* ad2     = (const float*)d_in[16];
    const float* g2      = (const float*)d_in[18];
    const float* be2     = (const float*)d_in[19];
    const float* fc1_w   = (const float*)d_in[20];
    const float* fc1_b   = (const float*)d_in[21];
    const float* fc2_w   = (const float*)d_in[22];
    const float* fc2_b   = (const float*)d_in[23];

    int N = in_sizes[0] / 64;
    int E = in_sizes[1] / 2;
    int OUT = in_sizes[23];
    int NB = (N + SCB - 1) / SCB;

    float* ws    = (float*)d_ws;
    float* h0    = ws;                      // N*H fp32
    float* hA    = h0 + (size_t)N * H;      // N*H region (bf16 for GAT layers / fp32 for fc1)
    float* agg   = hA + (size_t)N * H;      // N*H fp32
    float* al_s  = agg + (size_t)N * H;     // N
    float* al_d  = al_s + N;                // N
    float* accum = al_d + N;                // 512 (two BN accumulators)
    int* rowptr  = (int*)(accum + 512);     // N+1
    int* cnt     = rowptr + (N + 1);        // N
    int* cursor  = cnt + N;                 // N
    int* nodeoff = cursor + N;              // N
    int* blocksum= nodeoff + N;             // NB
    int* blockoff= blocksum + NB;           // NB
    int* ssrc    = blockoff + NB;           // E
    unsigned short* hAb = (unsigned short*)hA;

    const int* srcp = ei;
    const int* dstp = ei + E;

    dim3 b256(256);
    int gGemm = (N + 63) / 64;
    int gNH = (N * H + 255) / 256;
    int gWaveN = (N + 3) / 4;
    int gOwn = 512 * 8;

    // ---- fuse ----
    fuse_kernel<<<2048, b256, 0, stream>>>(x, sat_w, sat_b, neigh_w, neigh_b, fus_w, fus_b, h0, N);

    // ---- CSR build (XCD-ownership; real edges only) ----
    fill_u32<<<(N + 255) / 256, b256, 0, stream>>>((unsigned*)cnt, 0u, N);
    hist8<<<gOwn, b256, 0, stream>>>(dstp, cnt, E, N);
    scan_a<<<NB, SCB, 0, stream>>>(cnt, nodeoff, blocksum, N);
    scan_b<<<1, 1024, 0, stream>>>(blocksum, blockoff, rowptr + N, NB);
    scan_c<<<NB, SCB, 0, stream>>>(nodeoff, blockoff, rowptr, cursor, accum, N);
    scatter8<<<gOwn, b256, 0, stream>>>(srcp, dstp, cursor, ssrc, E, N);

    // ================= GAT layer 1 =================
    gemm128<1, 1><<<gGemm, b256, 0, stream>>>(h0, w1, nullptr, 0, hAb, N, as1, ad1, al_s, al_d);
    gat_agg<1><<<gWaveN, b256, 0, stream>>>(rowptr, ssrc, al_s, al_d, hAb, agg, N);
    bn_stats<<<512, b256, 0, stream>>>(agg, accum, N);
    bn_apply<<<gNH, b256, 0, stream>>>(agg, accum, g1, be1, h0, N);

    // ================= GAT layer 2 =================
    gemm128<2, 1><<<gGemm, b256, 0, stream>>>(agg, w2, nullptr, 0, hAb, N, as2, ad2, al_s, al_d);
    gat_agg<2><<<gWaveN, b256, 0, stream>>>(rowptr, ssrc, al_s, al_d, hAb, h0, N);
    bn_stats<<<512, b256, 0, stream>>>(h0, accum + 256, N);
    bn_apply<<<gNH, b256, 0, stream>>>(h0, accum + 256, g2, be2, agg, N);

    // ================= head =================
    gemm128<3, 0><<<gGemm, b256, 0, stream>>>(h0, fc1_w, fc1_b, 1, hA, N, nullptr, nullptr, nullptr, nullptr);
    fc2_kernel<<<(N + 15) / 16, b256, 0, stream>>>(hA, fc2_w, fc2_b, (float*)d_out, N, OUT);
}